// Round 1
// baseline (737.339 us; speedup 1.0000x reference)
//
#include <hip/hip_runtime.h>
#include <cstdint>

// Problem constants (fixed by reference):
#define Bc 1024
#define Tc 4096
#define Nc 2048
#define Kc 16
#define Mc 65536

// ---------------------------------------------------------------------------
// Pass 1: pack bit0 of memory[N][M] (int32) into a bitset in workspace.
//   Table shrinks 512 MB -> 16 MB (fits Infinity Cache; ~half of agg L2).
//   Streaming read, perfectly coalesced; ballot packs 64 bits per wave-iter.
//   Total: 512 MB read + 16 MB write ~= 85 us at ~6 TB/s.
// ---------------------------------------------------------------------------
#define PACK_GRID 2048
#define PACK_BLK  256
// elems/thread = Nc*Mc / (PACK_GRID*PACK_BLK) = 134217728 / 524288 = 256

__global__ __launch_bounds__(PACK_BLK) void pack_bit0(
    const int* __restrict__ memory,
    unsigned long long* __restrict__ packed)   // Nc*Mc/64 = 2M u64 = 16 MB
{
    const int tid  = threadIdx.x;
    const int lane = tid & 63;
    const size_t stride = (size_t)PACK_GRID * PACK_BLK;   // 524288
    size_t base = (size_t)blockIdx.x * PACK_BLK + tid;

    for (int it = 0; it < 256 / 8; ++it) {                // 32 outer iters
        int v[8];
#pragma unroll
        for (int j = 0; j < 8; ++j)                        // 8 loads in flight
            v[j] = __builtin_nontemporal_load(memory + base + (size_t)j * stride);
#pragma unroll
        for (int j = 0; j < 8; ++j) {
            const unsigned long long m = __ballot(v[j] & 1);
            if (lane == 0) {
                // lane0's elem index is 64-aligned (blockDim=256, stride%64==0)
                packed[(base + (size_t)j * stride) >> 6] = m;
            }
        }
        base += 8 * stride;
    }
}

// ---------------------------------------------------------------------------
// Pass 2: same structure as the verified kernel, but the gather now probes the
//   16 MB packed bitset (L2/L3-resident, ~8 uses per 64B line) instead of the
//   512 MB raw table (0.25 uses per line, random HBM).
//   word = packed32[(n << 11) + (a >> 5)], bit = a & 31.
// ---------------------------------------------------------------------------
__global__ __launch_bounds__(256) void ram_lookup_packed(
    const int* __restrict__ input_bits,       // (B, T) int32 in {0,1}
    const int* __restrict__ connections,      // (N, K) int32 in [0, T)
    const uint32_t* __restrict__ packed,      // Nc * (Mc/32) u32
    int* __restrict__ out)                    // (B, N) bool-as-int32
{
    __shared__ uint32_t bits[Tc / 32];        // 128 words = 512 B

    const int b    = blockIdx.x;
    const int tid  = threadIdx.x;
    const int lane = tid & 63;
    const int wave = tid >> 6;

    const int* row = input_bits + (size_t)b * Tc;

    // ---- Phase 1: build input bitset via ballot ----
#pragma unroll
    for (int i = 0; i < Tc / 256; ++i) {      // 16 iterations
        const int pos = i * 256 + wave * 64 + lane;
        const unsigned long long m = __ballot(row[pos] & 1);
        if (lane == 0) {
            const int w64 = i * 4 + wave;
            bits[w64 * 2]     = (uint32_t)m;
            bits[w64 * 2 + 1] = (uint32_t)(m >> 32);
        }
    }
    __syncthreads();

    // ---- Phase 2+3 fused: addr -> immediate packed-table probe ----
    int vals[Nc / 256];
#pragma unroll
    for (int i = 0; i < Nc / 256; ++i) {      // 8 independent probe chains
        const int n = i * 256 + tid;
        const int4* cp = (const int4*)(connections + n * Kc);
        const int4 c0 = cp[0], c1 = cp[1], c2 = cp[2], c3 = cp[3];
        const int c[16] = {c0.x, c0.y, c0.z, c0.w,
                           c1.x, c1.y, c1.z, c1.w,
                           c2.x, c2.y, c2.z, c2.w,
                           c3.x, c3.y, c3.z, c3.w};
        uint32_t a = 0;
#pragma unroll
        for (int k = 0; k < 16; ++k) {
            const uint32_t t = (uint32_t)c[k];
            a |= ((bits[t >> 5] >> (t & 31)) & 1u) << k;
        }
        const uint32_t w = packed[((uint32_t)n << 11) + (a >> 5)];
        vals[i] = (int)((w >> (a & 31)) & 1u);
    }

    // ---- Phase 4: coalesced stores ----
#pragma unroll
    for (int i = 0; i < Nc / 256; ++i) {
        __builtin_nontemporal_store(vals[i],
                                    out + (size_t)b * Nc + i * 256 + tid);
    }
}

// ---------------------------------------------------------------------------
// Fallback (previous verified kernel) in case ws_size < 16 MB.
// ---------------------------------------------------------------------------
__global__ __launch_bounds__(256) void ram_lookup_fused(
    const int* __restrict__ input_bits,
    const int* __restrict__ connections,
    const int* __restrict__ memory,
    int* __restrict__ out)
{
    __shared__ uint32_t bits[Tc / 32];

    const int b    = blockIdx.x;
    const int tid  = threadIdx.x;
    const int lane = tid & 63;
    const int wave = tid >> 6;

    const int* row = input_bits + (size_t)b * Tc;

#pragma unroll
    for (int i = 0; i < Tc / 256; ++i) {
        const int pos = i * 256 + wave * 64 + lane;
        const unsigned long long m = __ballot(row[pos] & 1);
        if (lane == 0) {
            const int w64 = i * 4 + wave;
            bits[w64 * 2]     = (uint32_t)m;
            bits[w64 * 2 + 1] = (uint32_t)(m >> 32);
        }
    }
    __syncthreads();

    int vals[Nc / 256];
#pragma unroll
    for (int i = 0; i < Nc / 256; ++i) {
        const int n = i * 256 + tid;
        const int4* cp = (const int4*)(connections + n * Kc);
        const int4 c0 = cp[0], c1 = cp[1], c2 = cp[2], c3 = cp[3];
        const int c[16] = {c0.x, c0.y, c0.z, c0.w,
                           c1.x, c1.y, c1.z, c1.w,
                           c2.x, c2.y, c2.z, c2.w,
                           c3.x, c3.y, c3.z, c3.w};
        uint32_t a = 0;
#pragma unroll
        for (int k = 0; k < 16; ++k) {
            const uint32_t t = (uint32_t)c[k];
            a |= ((bits[t >> 5] >> (t & 31)) & 1u) << k;
        }
        vals[i] = __builtin_nontemporal_load(memory + ((size_t)n << 16) + a);
    }

#pragma unroll
    for (int i = 0; i < Nc / 256; ++i) {
        __builtin_nontemporal_store(vals[i] & 1,
                                    out + (size_t)b * Nc + i * 256 + tid);
    }
}

extern "C" void kernel_launch(void* const* d_in, const int* in_sizes, int n_in,
                              void* d_out, int out_size, void* d_ws, size_t ws_size,
                              hipStream_t stream) {
    const int* input_bits  = (const int*)d_in[0];  // B*T
    const int* connections = (const int*)d_in[1];  // N*K
    const int* memory      = (const int*)d_in[2];  // N*M
    int* out               = (int*)d_out;          // B*N (bool -> int32)

    const size_t packed_bytes = (size_t)Nc * Mc / 8;   // 16 MB

    if (ws_size >= packed_bytes) {
        unsigned long long* packed64 = (unsigned long long*)d_ws;
        hipLaunchKernelGGL(pack_bit0, dim3(PACK_GRID), dim3(PACK_BLK), 0, stream,
                           memory, packed64);
        hipLaunchKernelGGL(ram_lookup_packed, dim3(Bc), dim3(256), 0, stream,
                           input_bits, connections, (const uint32_t*)d_ws, out);
    } else {
        hipLaunchKernelGGL(ram_lookup_fused, dim3(Bc), dim3(256), 0, stream,
                           input_bits, connections, memory, out);
    }
}

// Round 4
// 675.137 us; speedup vs baseline: 1.0921x; 1.0921x over previous
//
#include <hip/hip_runtime.h>
#include <cstdint>

// Problem constants (fixed by reference):
#define Bc 1024
#define Tc 4096
#define Nc 2048
#define Kc 16
#define Mc 65536

#define Gn 8               // memory rows per block in probe kernel
#define GRID_B (Nc / Gn)   // 256 blocks = 1 per CU

// clang ext_vector types (HIP_vector_type int4 is NOT accepted by
// __builtin_nontemporal_load/store).
typedef int  v4i  __attribute__((ext_vector_type(4)));
typedef uint v4u  __attribute__((ext_vector_type(4)));

// ---------------------------------------------------------------------------
// Kernel A (b-major): compute all 16-bit addresses, store u16 to workspace.
// Identical verified structure to the baseline kernel's phases 1-2; the
// divergent gather is replaced by a coalesced u16 store.
// ---------------------------------------------------------------------------
__global__ __launch_bounds__(256) void addr_kernel(
    const int* __restrict__ input_bits,     // (B, T)
    const int* __restrict__ connections,    // (N, K)
    unsigned short* __restrict__ addr)      // (B, N) u16
{
    __shared__ uint32_t bits[Tc / 32];      // 512 B

    const int b    = blockIdx.x;
    const int tid  = threadIdx.x;
    const int lane = tid & 63;
    const int wave = tid >> 6;

    const int* row = input_bits + (size_t)b * Tc;

#pragma unroll
    for (int i = 0; i < Tc / 256; ++i) {    // 16 iterations
        const int pos = i * 256 + wave * 64 + lane;
        const unsigned long long m = __ballot(row[pos] & 1);
        if (lane == 0) {
            const int w64 = i * 4 + wave;
            bits[w64 * 2]     = (uint32_t)m;
            bits[w64 * 2 + 1] = (uint32_t)(m >> 32);
        }
    }
    __syncthreads();

#pragma unroll
    for (int i = 0; i < Nc / 256; ++i) {    // 8 iterations
        const int n = i * 256 + tid;
        const int4* cp = (const int4*)(connections + n * Kc);
        const int4 c0 = cp[0], c1 = cp[1], c2 = cp[2], c3 = cp[3];
        const int c[16] = {c0.x, c0.y, c0.z, c0.w,
                           c1.x, c1.y, c1.z, c1.w,
                           c2.x, c2.y, c2.z, c2.w,
                           c3.x, c3.y, c3.z, c3.w};
        uint32_t a = 0;
#pragma unroll
        for (int k = 0; k < 16; ++k) {
            const uint32_t t = (uint32_t)c[k];
            a |= ((bits[t >> 5] >> (t & 31)) & 1u) << k;
        }
        addr[(size_t)b * Nc + n] = (unsigned short)a;   // coalesced 128B/wave
    }
}

// ---------------------------------------------------------------------------
// Kernel B (n-major): each block owns 8 memory rows. Phase 1 streams the
// 2 MB of raw rows (perfectly coalesced 16B loads) and ballot-packs bit0 into
// a 64 KB LDS bitset. Phase 2 probes LDS for all 1024 batches.
//
// Packed layout (matches wave ballot order):
//   chunk q = 256 elements (one wave 16B-iteration). Element e in chunk:
//   lane l = e>>2, component c = e&3. ballot(comp c) bit l.
//   word index within row = (q&255)*8 + c*2 + (l>>5), bit = l&31.
//   Probe for address a: idx = (a>>8)*8 + (a&3)*2 + ((a>>7)&1); bit=(a>>2)&31.
//
// Chunk assignment: wave w owns the contiguous quarter [w*512, (w+1)*512),
// processed 8 chunks per iteration (8 x 1KB loads in flight = 32 KB/CU MLP).
// 64 iterations x 4 waves x 8 chunks = 2048 chunks total.  (Round-3 bug was
// covering only 512 chunks.)
// ---------------------------------------------------------------------------
__global__ __launch_bounds__(256) void probe_kernel(
    const int* __restrict__ memory,          // (N, M)
    const unsigned short* __restrict__ addr, // (B, N)
    int* __restrict__ out)                   // (B, N) bool-as-int32
{
    __shared__ uint32_t prow[Gn][Mc / 32];   // 8 x 2048 words = 64 KB

    const int n0   = blockIdx.x * Gn;
    const int tid  = threadIdx.x;
    const int lane = tid & 63;
    const int wave = tid >> 6;

    // ---- Phase 1: stream + ballot-pack ----
    for (int j = 0; j < 64; ++j) {
        const int qb = wave * 512 + j * 8;   // this wave's 8 chunks
        v4i v[8];
#pragma unroll
        for (int u = 0; u < 8; ++u) {        // 8 independent loads in flight
            const int q = qb + u;
            const int r = q >> 8;            // row in group
            const int it = q & 255;          // chunk within row
            v[u] = __builtin_nontemporal_load(
                (const v4i*)(memory + (size_t)(n0 + r) * Mc) + it * 64 + lane);
        }
#pragma unroll
        for (int u = 0; u < 8; ++u) {
            const int q = qb + u;
            const unsigned long long m0 = __ballot(v[u].x & 1);
            const unsigned long long m1 = __ballot(v[u].y & 1);
            const unsigned long long m2 = __ballot(v[u].z & 1);
            const unsigned long long m3 = __ballot(v[u].w & 1);
            if (lane < 8) {
                const int c = lane >> 1;
                const unsigned long long mm =
                    (c == 0) ? m0 : (c == 1) ? m1 : (c == 2) ? m2 : m3;
                prow[q >> 8][(q & 255) * 8 + lane] =
                    (uint32_t)(mm >> ((lane & 1) << 5));
            }
        }
    }
    __syncthreads();

    // ---- Phase 2: probe LDS for all 1024 b's, 8 n's per thread-iteration.
#pragma unroll
    for (int j = 0; j < 4; ++j) {
        const int b = j * 256 + tid;
        // 8 consecutive u16 addresses = 16 B vector load
        const v4u av = *(const v4u*)(addr + (size_t)b * Nc + n0);
        const uint32_t aw[4] = {av.x, av.y, av.z, av.w};
        int res[8];
#pragma unroll
        for (int p = 0; p < 8; ++p) {
            const uint32_t a   = (aw[p >> 1] >> ((p & 1) * 16)) & 0xffffu;
            const uint32_t idx = ((a >> 8) << 3) + ((a & 3) << 1) + ((a >> 7) & 1);
            res[p] = (int)((prow[p][idx] >> ((a >> 2) & 31)) & 1u);
        }
        v4i* op = (v4i*)(out + (size_t)b * Nc + n0);
        v4i r0 = {res[0], res[1], res[2], res[3]};
        v4i r1 = {res[4], res[5], res[6], res[7]};
        __builtin_nontemporal_store(r0, op);
        __builtin_nontemporal_store(r1, op + 1);
    }
}

// ---------------------------------------------------------------------------
// Fallback (previous verified kernel) in case ws_size < 4 MB.
// ---------------------------------------------------------------------------
__global__ __launch_bounds__(256) void ram_lookup_fused(
    const int* __restrict__ input_bits,
    const int* __restrict__ connections,
    const int* __restrict__ memory,
    int* __restrict__ out)
{
    __shared__ uint32_t bits[Tc / 32];

    const int b    = blockIdx.x;
    const int tid  = threadIdx.x;
    const int lane = tid & 63;
    const int wave = tid >> 6;

    const int* row = input_bits + (size_t)b * Tc;

#pragma unroll
    for (int i = 0; i < Tc / 256; ++i) {
        const int pos = i * 256 + wave * 64 + lane;
        const unsigned long long m = __ballot(row[pos] & 1);
        if (lane == 0) {
            const int w64 = i * 4 + wave;
            bits[w64 * 2]     = (uint32_t)m;
            bits[w64 * 2 + 1] = (uint32_t)(m >> 32);
        }
    }
    __syncthreads();

    int vals[Nc / 256];
#pragma unroll
    for (int i = 0; i < Nc / 256; ++i) {
        const int n = i * 256 + tid;
        const int4* cp = (const int4*)(connections + n * Kc);
        const int4 c0 = cp[0], c1 = cp[1], c2 = cp[2], c3 = cp[3];
        const int c[16] = {c0.x, c0.y, c0.z, c0.w,
                           c1.x, c1.y, c1.z, c1.w,
                           c2.x, c2.y, c2.z, c2.w,
                           c3.x, c3.y, c3.z, c3.w};
        uint32_t a = 0;
#pragma unroll
        for (int k = 0; k < 16; ++k) {
            const uint32_t t = (uint32_t)c[k];
            a |= ((bits[t >> 5] >> (t & 31)) & 1u) << k;
        }
        vals[i] = __builtin_nontemporal_load(memory + ((size_t)n << 16) + a);
    }

#pragma unroll
    for (int i = 0; i < Nc / 256; ++i) {
        __builtin_nontemporal_store(vals[i] & 1,
                                    out + (size_t)b * Nc + i * 256 + tid);
    }
}

extern "C" void kernel_launch(void* const* d_in, const int* in_sizes, int n_in,
                              void* d_out, int out_size, void* d_ws, size_t ws_size,
                              hipStream_t stream) {
    const int* input_bits  = (const int*)d_in[0];  // B*T
    const int* connections = (const int*)d_in[1];  // N*K
    const int* memory      = (const int*)d_in[2];  // N*M
    int* out               = (int*)d_out;          // B*N (bool -> int32)

    const size_t addr_bytes = (size_t)Bc * Nc * sizeof(unsigned short); // 4 MB

    if (ws_size >= addr_bytes) {
        unsigned short* addr = (unsigned short*)d_ws;
        hipLaunchKernelGGL(addr_kernel, dim3(Bc), dim3(256), 0, stream,
                           input_bits, connections, addr);
        hipLaunchKernelGGL(probe_kernel, dim3(GRID_B), dim3(256), 0, stream,
                           memory, addr, out);
    } else {
        hipLaunchKernelGGL(ram_lookup_fused, dim3(Bc), dim3(256), 0, stream,
                           input_bits, connections, memory, out);
    }
}